// Round 5
// baseline (304.253 us; speedup 1.0000x reference)
//
#include <hip/hip_runtime.h>
#include <hip/hip_bf16.h>

typedef short s16x8 __attribute__((ext_vector_type(8)));
typedef float f32x16 __attribute__((ext_vector_type(16)));

namespace {
constexpr int kB = 16;
constexpr int kD = 256;
constexpr int kHW = 16384;
constexpr int kM = 4096;
constexpr int kN = kB * kM;             // 65536 samples
constexpr int kKChunk = 1024;
constexpr int kNChunks = kN / kKChunk;  // 64
constexpr float kLam = 0.005f;
}

// ---------------------------------------------------------------------------
// Kernel 1: per-(input, b, d) plane gather + partial stats — DIRECT gather,
// no LDS staging.  Samples hit ~4 per 64B line and all uses of a line come
// from this block, so each line is fetched from HBM once and reused via
// L1/L2.  No LDS -> 8 blocks/CU resident, 16 independent loads per thread
// in flight -> HBM latency hidden (unlike the phased 64KB-plane staging,
// which lock-stepped 2 blocks/CU and idled HBM every gather phase).
// ---------------------------------------------------------------------------
__global__ __launch_bounds__(256) void gather_stats_kernel(
    const float* __restrict__ z, const float* __restrict__ zp,
    const int* __restrict__ flat_idx,
    __hip_bfloat16* __restrict__ Ag, __hip_bfloat16* __restrict__ Bg,
    float* __restrict__ Sp, float* __restrict__ SSp)
{
    const int bx = blockIdx.x;
    const int sel = bx >> 12;               // 0: z, 1: z_prime
    const int b = (bx >> 8) & (kB - 1);
    const int d = bx & (kD - 1);
    const int t = threadIdx.x;

    const float* __restrict__ plane = (sel ? zp : z) + ((size_t)(b * kD + d)) * kHW;
    const int* __restrict__ bi = flat_idx + b * kM;

    // 16 indices per thread (coalesced int4 loads, L2-resident across blocks)
    // int4-load of bi: thread t, iter i covers samples m = 4*(t+i*256)+j.
    int idx[16];
#pragma unroll
    for (int i = 0; i < 4; ++i) {
        const int4 q = ((const int4*)bi)[t + i * 256];
        idx[4 * i + 0] = q.x; idx[4 * i + 1] = q.y;
        idx[4 * i + 2] = q.z; idx[4 * i + 3] = q.w;
    }

    // Issue all 16 gather loads back-to-back (independent -> 16 in flight)
    float v[16];
#pragma unroll
    for (int i = 0; i < 16; ++i) v[i] = plane[idx[i]];

    __hip_bfloat16* dst = (sel ? Bg : Ag) + (size_t)d * kN + b * kM;
    float s = 0.f, ss = 0.f;
#pragma unroll
    for (int i = 0; i < 16; ++i) { s += v[i]; ss += v[i] * v[i]; }

#pragma unroll
    for (int i = 0; i < 4; ++i) {
        const int m0 = 4 * (t + i * 256);
        __hip_bfloat16 h[4];
#pragma unroll
        for (int j = 0; j < 4; ++j) h[j] = __float2bfloat16(v[4 * i + j]);
        *(ushort4*)(dst + m0) = *(const ushort4*)h;   // 8B/thread, coalesced
    }

    // wave reduce + cross-wave via tiny LDS
#pragma unroll
    for (int o = 32; o; o >>= 1) {
        s += __shfl_down(s, o);
        ss += __shfl_down(ss, o);
    }
    __shared__ float red[8];
    if ((t & 63) == 0) { red[t >> 6] = s; red[4 + (t >> 6)] = ss; }
    __syncthreads();
    if (t == 0) {
        const int slot = (sel * kB + b) * kD + d;
        Sp[slot]  = red[0] + red[1] + red[2] + red[3];
        SSp[slot] = red[4] + red[5] + red[6] + red[7];
    }
}

// ---------------------------------------------------------------------------
// Kernel 2: partial Gram GEMM.  G = A * B^T where A, B are [D][N] bf16
// (feature-major).  Grid = 16 C-tiles (64x64) x 64 K-chunks (1024).
// Block = 4 waves (2x2 of 32x32 MFMA tiles).  Deterministic partials to ws.
// ---------------------------------------------------------------------------
__global__ __launch_bounds__(256) void gemm_part_kernel(
    const __hip_bfloat16* __restrict__ Ag, const __hip_bfloat16* __restrict__ Bg,
    float* __restrict__ partial)
{
    const int bx = blockIdx.x;
    const int tile = bx & 15;
    const int chunk = bx >> 4;
    const int tr = (tile >> 2) * 64;
    const int tc = (tile & 3) * 64;
    const int tid = threadIdx.x;
    const int wid = tid >> 6;
    const int lane = tid & 63;
    const int l31 = lane & 31;
    const int half = lane >> 5;
    const int d0 = tr + (wid >> 1) * 32;
    const int e0 = tc + (wid & 1) * 32;

    const __hip_bfloat16* arow = Ag + (size_t)(d0 + l31) * kN;
    const __hip_bfloat16* brow = Bg + (size_t)(e0 + l31) * kN;
    int kb = chunk * kKChunk + half * 8;

    f32x16 acc;
#pragma unroll
    for (int i = 0; i < 16; ++i) acc[i] = 0.f;

#pragma unroll 8
    for (int it = 0; it < kKChunk / 16; ++it) {
        // A-operand 32x32x16: lane l holds A[l&31][(l>>5)*8 + j], j=0..7
        s16x8 a = *(const s16x8*)(arow + kb);
        // B-operand: lane l holds B[(l>>5)*8 + j][l&31]; with Bg feature-major
        // this is the same contiguous 16B load.
        s16x8 bf = *(const s16x8*)(brow + kb);
        acc = __builtin_amdgcn_mfma_f32_32x32x16_bf16(a, bf, acc, 0, 0, 0);
        kb += 16;
    }

    float* out = partial + (size_t)chunk * (kD * kD);
#pragma unroll
    for (int r = 0; r < 16; ++r) {
        // C/D layout (verified m74/m101): col = lane&31, row = (r&3)+8*(r>>2)+4*(lane>>5)
        const int row = (r & 3) + 8 * (r >> 2) + 4 * half;
        out[(d0 + row) * kD + (e0 + l31)] = acc[r];
    }
}

// ---------------------------------------------------------------------------
// Kernel 3: reduce K-chunk partials -> G (256x256 f32)
// ---------------------------------------------------------------------------
__global__ __launch_bounds__(256) void reduce_gram_kernel(
    const float* __restrict__ partial, float* __restrict__ G)
{
    const int d = blockIdx.x;
    const int e = threadIdx.x;
    float s = 0.f;
#pragma unroll 8
    for (int c = 0; c < kNChunks; ++c)
        s += partial[(size_t)c * (kD * kD) + d * kD + e];
    G[d * kD + e] = s;
}

// ---------------------------------------------------------------------------
// Kernel 4: final loss.  Single block.
// C_de = (G_de/N - mu_d nu_e) / (sd_d sd_e);  loss = sum((1-diag)^2) + lam*sum(off^2)
// ---------------------------------------------------------------------------
__global__ __launch_bounds__(256) void loss_kernel(
    const float* __restrict__ G, const float* __restrict__ Sp,
    const float* __restrict__ SSp, float* __restrict__ out)
{
    __shared__ float muA[kD], isA[kD], muB[kD], isB[kD];
    const int t = threadIdx.x;
    float sA = 0.f, ssA = 0.f, sB = 0.f, ssB = 0.f;
#pragma unroll
    for (int b = 0; b < kB; ++b) {
        sA  += Sp [(0 * kB + b) * kD + t];
        ssA += SSp[(0 * kB + b) * kD + t];
        sB  += Sp [(1 * kB + b) * kD + t];
        ssB += SSp[(1 * kB + b) * kD + t];
    }
    const float n = (float)kN;
    const float mA = sA / n, mB = sB / n;
    float vA = (ssA - n * mA * mA) / (n - 1.f);
    float vB = (ssB - n * mB * mB) / (n - 1.f);
    float sdA = fmaxf(sqrtf(fmaxf(vA, 0.f)), 1e-6f);
    float sdB = fmaxf(sqrtf(fmaxf(vB, 0.f)), 1e-6f);
    muA[t] = mA; isA[t] = 1.f / sdA;
    muB[t] = mB; isB[t] = 1.f / sdB;
    __syncthreads();

    float acc = 0.f;
    for (int d = 0; d < kD; ++d) {
        const int e = t;
        const float c = (G[d * kD + e] / n - muA[d] * muB[e]) * isA[d] * isB[e];
        if (d == e) { const float u = 1.f - c; acc += u * u; }
        else        { acc += kLam * c * c; }
    }
#pragma unroll
    for (int o = 32; o; o >>= 1) acc += __shfl_down(acc, o);
    __shared__ float r[4];
    if ((t & 63) == 0) r[t >> 6] = acc;
    __syncthreads();
    if (t == 0) out[0] = r[0] + r[1] + r[2] + r[3];
}

// ---------------------------------------------------------------------------
extern "C" void kernel_launch(void* const* d_in, const int* in_sizes, int n_in,
                              void* d_out, int out_size, void* d_ws, size_t ws_size,
                              hipStream_t stream) {
    const float* z  = (const float*)d_in[0];
    const float* zp = (const float*)d_in[1];
    const int* flat_idx = (const int*)d_in[2];
    float* out = (float*)d_out;

    char* ws = (char*)d_ws;
    // ws layout:
    //   [0,   32MB)  Ag  bf16 [256][65536]
    //   [32,  64MB)  Bg  bf16 [256][65536]
    //   [64,  80MB)  partial f32 [64][256][256]
    //   [80MB, +32K) Sp  f32 [2][16][256]
    //   ..   +32K    SSp
    //   ..   +256K   G   f32 [256][256]
    __hip_bfloat16* Ag = (__hip_bfloat16*)ws;
    __hip_bfloat16* Bg = (__hip_bfloat16*)(ws + (size_t)32 * 1024 * 1024);
    float* partial = (float*)(ws + (size_t)64 * 1024 * 1024);
    float* Sp  = (float*)(ws + (size_t)80 * 1024 * 1024);
    float* SSp = Sp + 2 * kB * kD;
    float* G   = (float*)(ws + (size_t)80 * 1024 * 1024 + 64 * 1024);

    gather_stats_kernel<<<2 * kB * kD, 256, 0, stream>>>(z, zp, flat_idx, Ag, Bg, Sp, SSp);
    gemm_part_kernel<<<16 * kNChunks, 256, 0, stream>>>(Ag, Bg, partial);
    reduce_gram_kernel<<<kD, 256, 0, stream>>>(partial, G);
    loss_kernel<<<1, 256, 0, stream>>>(G, Sp, SSp, out);
}

// Round 6
// 252.823 us; speedup vs baseline: 1.2034x; 1.2034x over previous
//
#include <hip/hip_runtime.h>
#include <hip/hip_bf16.h>

typedef short s16x8 __attribute__((ext_vector_type(8)));
typedef float f32x16 __attribute__((ext_vector_type(16)));

namespace {
constexpr int kB = 16;
constexpr int kD = 256;
constexpr int kHW = 16384;
constexpr int kM = 4096;
constexpr int kN = kB * kM;             // 65536 samples
constexpr int kWin = 1024;              // columns per block
constexpr int kNBlk = kB * (kHW / kWin); // 256 partial-Gram blocks
constexpr float kLam = 0.005f;

// round-to-nearest-even f32 -> bf16 bits (self-contained, no hip_bf16 API risk)
__device__ __forceinline__ unsigned short f2bf(float f) {
    union { float f; unsigned u; } x{f};
    const unsigned r = x.u + 0x7FFFu + ((x.u >> 16) & 1u);
    return (unsigned short)(r >> 16);
}
}

// ---------------------------------------------------------------------------
// Kernel 1: per-b histogram of flat_idx -> counts c[b][p].
// LDS integer atomics (deterministic), one block per b.
// ---------------------------------------------------------------------------
__global__ __launch_bounds__(256) void count_kernel(
    const int* __restrict__ flat_idx, int* __restrict__ cnt)
{
    __shared__ int h[kHW];   // 64 KiB
    const int t = threadIdx.x;
    const int b = blockIdx.x;
    for (int i = t; i < kHW; i += 256) h[i] = 0;
    __syncthreads();
    const int* bi = flat_idx + b * kM;
    for (int i = t; i < kM; i += 256) atomicAdd(&h[bi[i]], 1);
    __syncthreads();
    int* dst = cnt + b * kHW;
    for (int i = t; i < kHW; i += 256) dst[i] = h[i];
}

// ---------------------------------------------------------------------------
// Kernel 2: fused stream + weighted Gram + stats.
// Block bx: b = bx&15, window = (bx>>4)*1024 columns. Streams z / z' tiles
// (256 rows x 64 cols f32, coalesced float4), computes f32 weighted stats,
// stages bf16 tiles to XOR-swizzled LDS (A raw, B weighted by c), MFMA
// 256x256 Gram partial over K=1024, writes partial + stats partials.
// ---------------------------------------------------------------------------
__global__ __launch_bounds__(512, 2) void fused_gram_kernel(
    const float* __restrict__ z, const float* __restrict__ zp,
    const int* __restrict__ cnt,
    float* __restrict__ partial, float* __restrict__ statsPart)
{
    __shared__ char smem[65536];
    __hip_bfloat16* As = (__hip_bfloat16*)smem;            // [256][64] swizzled
    __hip_bfloat16* Bs = (__hip_bfloat16*)(smem + 32768);  // [256][64] swizzled

    const int bx = blockIdx.x;
    const int b = bx & (kB - 1);
    const int win0 = (bx >> 4) * kWin;
    const int t = threadIdx.x;
    const int w = t >> 6;
    const int lane = t & 63;
    const int l31 = lane & 31;
    const int half = lane >> 5;
    const int wr = w >> 2;          // 0..1  (row block of 128)
    const int wc = w & 3;           // 0..3  (col block of 64)

    const int rbase = t >> 4;       // staging row within 32-row group
    const int cg = t & 15;          // staging col group (4 f32)

    const float* zb  = z  + (size_t)b * kD * kHW;
    const float* zpb = zp + (size_t)b * kD * kHW;
    const int* cb = cnt + b * kHW;

    f32x16 acc[4][2];
#pragma unroll
    for (int i = 0; i < 4; ++i)
#pragma unroll
        for (int j = 0; j < 2; ++j)
#pragma unroll
            for (int r = 0; r < 16; ++r) acc[i][j][r] = 0.f;

    float sA[8], ssA[8], sB[8], ssB[8];
#pragma unroll
    for (int q = 0; q < 8; ++q) { sA[q] = ssA[q] = sB[q] = ssB[q] = 0.f; }

    for (int kt = 0; kt < kWin / 64; ++kt) {
        const int p0 = win0 + kt * 64;
        // counts for this thread's 4 columns (fixed across the 8 row-passes)
        const int4 ci = *(const int4*)(cb + p0 + cg * 4);
        const float cf[4] = {(float)ci.x, (float)ci.y, (float)ci.z, (float)ci.w};

#pragma unroll
        for (int q = 0; q < 8; ++q) {
            const int r = 32 * q + rbase;
            const size_t goff = (size_t)r * kHW + p0 + cg * 4;
            const float4 vA = *(const float4*)(zb + goff);
            const float4 vB = *(const float4*)(zpb + goff);
            const float a[4] = {vA.x, vA.y, vA.z, vA.w};
            const float bb[4] = {vB.x, vB.y, vB.z, vB.w};
            ushort4 pa, pb;
            unsigned short* pav = (unsigned short*)&pa;
            unsigned short* pbv = (unsigned short*)&pb;
#pragma unroll
            for (int j = 0; j < 4; ++j) {
                const float wa = cf[j] * a[j];
                const float wb = cf[j] * bb[j];
                sA[q] += wa; ssA[q] += wa * a[j];
                sB[q] += wb; ssB[q] += wb * bb[j];
                pav[j] = f2bf(a[j]);    // A staged raw
                pbv[j] = f2bf(wb);      // B staged weighted
            }
            // swizzled LDS write: row r, 16B-slot = (cg>>1)^(r&7), half 8B = cg&1
            const int off = r * 128 + (((cg >> 1) ^ (r & 7)) << 4) + ((cg & 1) << 3);
            *(ushort4*)(smem + off) = pa;           // As
            *(ushort4*)(smem + 32768 + off) = pb;   // Bs
        }
        __syncthreads();

        // MFMA phase: wave (wr,wc) owns rows 128wr..+128, cols 64wc..+64
#pragma unroll
        for (int ks = 0; ks < 4; ++ks) {
            s16x8 af[4], bf[2];
#pragma unroll
            for (int rt = 0; rt < 4; ++rt) {
                const int row = 128 * wr + 32 * rt + l31;
                const int slot = (2 * ks + half) ^ (row & 7);
                af[rt] = *(const s16x8*)(smem + row * 128 + slot * 16);
            }
#pragma unroll
            for (int ct = 0; ct < 2; ++ct) {
                const int row = 64 * wc + 32 * ct + l31;
                const int slot = (2 * ks + half) ^ (row & 7);
                bf[ct] = *(const s16x8*)(smem + 32768 + row * 128 + slot * 16);
            }
#pragma unroll
            for (int rt = 0; rt < 4; ++rt)
#pragma unroll
                for (int ct = 0; ct < 2; ++ct)
                    acc[rt][ct] = __builtin_amdgcn_mfma_f32_32x32x16_bf16(
                        af[rt], bf[ct], acc[rt][ct], 0, 0, 0);
        }
        __syncthreads();
    }

    // write 256x256 partial Gram
    float* out = partial + (size_t)bx * (kD * kD);
#pragma unroll
    for (int rt = 0; rt < 4; ++rt)
#pragma unroll
        for (int ct = 0; ct < 2; ++ct)
#pragma unroll
            for (int r = 0; r < 16; ++r) {
                const int row = 128 * wr + 32 * rt + (r & 3) + 8 * (r >> 2) + 4 * half;
                const int col = 64 * wc + 32 * ct + l31;
                out[row * kD + col] = acc[rt][ct][r];
            }

    // stats: dump per-thread partials to (now dead) LDS, reduce over 16 colgroups
    float* sd = (float*)smem;   // [256 rows][16 cg][4 kinds] = 64 KiB
    __syncthreads();
#pragma unroll
    for (int q = 0; q < 8; ++q) {
        const int row = 32 * q + rbase;
        float* p = sd + (row * 16 + cg) * 4;
        p[0] = sA[q]; p[1] = ssA[q]; p[2] = sB[q]; p[3] = ssB[q];
    }
    __syncthreads();
    {
        const int row = t >> 1;
        const int pair = t & 1;     // kinds {0,1} or {2,3}
        float a0 = 0.f, a1 = 0.f;
#pragma unroll
        for (int g = 0; g < 16; ++g) {
            a0 += sd[(row * 16 + g) * 4 + 2 * pair];
            a1 += sd[(row * 16 + g) * 4 + 2 * pair + 1];
        }
        float* p = statsPart + ((size_t)bx * kD + row) * 4;
        p[2 * pair] = a0;
        p[2 * pair + 1] = a1;
    }
}

// ---------------------------------------------------------------------------
// Kernel 3: reduce partial Grams -> G (256x256 f32)
// ---------------------------------------------------------------------------
__global__ __launch_bounds__(256) void reduce_gram_kernel(
    const float* __restrict__ partial, float* __restrict__ G)
{
    const int d = blockIdx.x;
    const int e = threadIdx.x;
    float s = 0.f;
#pragma unroll 8
    for (int c = 0; c < kNBlk; ++c)
        s += partial[(size_t)c * (kD * kD) + d * kD + e];
    G[d * kD + e] = s;
}

// ---------------------------------------------------------------------------
// Kernel 4: final loss (single block). Reduces statsPart, forms C, loss.
// ---------------------------------------------------------------------------
__global__ __launch_bounds__(256) void loss_kernel(
    const float* __restrict__ G, const float* __restrict__ statsPart,
    float* __restrict__ out)
{
    __shared__ float muA[kD], isA[kD], muB[kD], isB[kD];
    const int t = threadIdx.x;
    float sA = 0.f, ssA = 0.f, sB = 0.f, ssB = 0.f;
    for (int blk = 0; blk < kNBlk; ++blk) {
        const float4 v = *(const float4*)(statsPart + ((size_t)blk * kD + t) * 4);
        sA += v.x; ssA += v.y; sB += v.z; ssB += v.w;
    }
    const float n = (float)kN;
    const float mA = sA / n, mB = sB / n;
    const float vA = (ssA - n * mA * mA) / (n - 1.f);
    const float vB = (ssB - n * mB * mB) / (n - 1.f);
    const float sdA = fmaxf(sqrtf(fmaxf(vA, 0.f)), 1e-6f);
    const float sdB = fmaxf(sqrtf(fmaxf(vB, 0.f)), 1e-6f);
    muA[t] = mA; isA[t] = 1.f / sdA;
    muB[t] = mB; isB[t] = 1.f / sdB;
    __syncthreads();

    float acc = 0.f;
    for (int d = 0; d < kD; ++d) {
        const int e = t;
        const float c = (G[d * kD + e] / n - muA[d] * muB[e]) * isA[d] * isB[e];
        if (d == e) { const float u = 1.f - c; acc += u * u; }
        else        { acc += kLam * c * c; }
    }
#pragma unroll
    for (int o = 32; o; o >>= 1) acc += __shfl_down(acc, o);
    __shared__ float r[4];
    if ((t & 63) == 0) r[t >> 6] = acc;
    __syncthreads();
    if (t == 0) out[0] = r[0] + r[1] + r[2] + r[3];
}

// ---------------------------------------------------------------------------
extern "C" void kernel_launch(void* const* d_in, const int* in_sizes, int n_in,
                              void* d_out, int out_size, void* d_ws, size_t ws_size,
                              hipStream_t stream) {
    const float* z  = (const float*)d_in[0];
    const float* zp = (const float*)d_in[1];
    const int* flat_idx = (const int*)d_in[2];
    float* out = (float*)d_out;

    char* ws = (char*)d_ws;
    // ws layout:
    //   [0, 1MB)    counts  int [16][16384]
    //   [1MB, 2MB)  statsPart f32 [256][256][4]
    //   [2MB, +256K) G f32 [256][256]
    //   [16MB, 80MB) partial f32 [256][256][256]
    int* cnt = (int*)ws;
    float* statsPart = (float*)(ws + (size_t)1 * 1024 * 1024);
    float* G = (float*)(ws + (size_t)2 * 1024 * 1024);
    float* partial = (float*)(ws + (size_t)16 * 1024 * 1024);

    count_kernel<<<kB, 256, 0, stream>>>(flat_idx, cnt);
    fused_gram_kernel<<<kNBlk, 512, 0, stream>>>(z, zp, cnt, partial, statsPart);
    reduce_gram_kernel<<<kD, 256, 0, stream>>>(partial, G);
    loss_kernel<<<1, 256, 0, stream>>>(G, statsPart, out);
}

// Round 7
// 182.062 us; speedup vs baseline: 1.6711x; 1.3887x over previous
//
#include <hip/hip_runtime.h>
#include <hip/hip_bf16.h>

typedef short s16x8 __attribute__((ext_vector_type(8)));
typedef float f32x16 __attribute__((ext_vector_type(16)));

namespace {
constexpr int kB = 16;
constexpr int kD = 256;
constexpr int kHW = 16384;
constexpr int kM = 4096;
constexpr int kN = kB * kM;              // 65536 samples
constexpr int kWin = 1024;               // columns per block
constexpr int kNBlk = kB * (kHW / kWin); // 256 blocks
constexpr int kKT = 32;                  // K-tile columns
constexpr int kNIter = kWin / kKT;       // 32 iterations
constexpr float kLam = 0.005f;

// round-to-nearest-even f32 -> bf16 bits
__device__ __forceinline__ unsigned short f2bf(float f) {
    union { float f; unsigned u; } x{f};
    const unsigned r = x.u + 0x7FFFu + ((x.u >> 16) & 1u);
    return (unsigned short)(r >> 16);
}
}

// ---------------------------------------------------------------------------
// Kernel 1: per-b histogram of flat_idx -> counts c[b][p].
// ---------------------------------------------------------------------------
__global__ __launch_bounds__(256) void count_kernel(
    const int* __restrict__ flat_idx, int* __restrict__ cnt)
{
    __shared__ int h[kHW];   // 64 KiB
    const int t = threadIdx.x;
    const int b = blockIdx.x;
    for (int i = t; i < kHW; i += 256) h[i] = 0;
    __syncthreads();
    const int* bi = flat_idx + b * kM;
    for (int i = t; i < kM; i += 256) atomicAdd(&h[bi[i]], 1);
    __syncthreads();
    int* dst = cnt + b * kHW;
    for (int i = t; i < kHW; i += 256) dst[i] = h[i];
}

// ---------------------------------------------------------------------------
// Kernel 2: fused stream + weighted Gram + stats, software-pipelined.
// Per iter: MFMA(buf) | bar | CONVERT(regs->LDS other buf) | LOAD(+2 into
// regs) | bar.  Loads issue a full iteration before their wait -> memory
// pipe continuously fed; double-buffered LDS (2 x 32KB).
// ---------------------------------------------------------------------------
__global__ __launch_bounds__(512, 2) void fused_gram_kernel(
    const float* __restrict__ z, const float* __restrict__ zp,
    const int* __restrict__ cnt,
    float* __restrict__ partial, float* __restrict__ statsPart)
{
    __shared__ char smem[65536];   // buf0: A[0,16K) B[16K,32K); buf1: +32K

    const int bx = blockIdx.x;
    const int b = bx & (kB - 1);
    const int win0 = (bx >> 4) * kWin;
    const int t = threadIdx.x;
    const int w = t >> 6, lane = t & 63, l31 = lane & 31, half = lane >> 5;
    const int wr = w >> 2;          // 0..1  row block of 128
    const int wc = w & 3;           // 0..3  col block of 64
    const int rbase = t >> 3;       // 0..63 staging row within 64-row group
    const int cg = t & 7;           // 0..7  staging col group (4 f32)

    const float* zb  = z  + (size_t)b * kD * kHW;
    const float* zpb = zp + (size_t)b * kD * kHW;
    const int* cb = cnt + b * kHW;

    f32x16 acc[4][2];
#pragma unroll
    for (int i = 0; i < 4; ++i)
#pragma unroll
        for (int j = 0; j < 2; ++j)
#pragma unroll
            for (int r = 0; r < 16; ++r) acc[i][j][r] = 0.f;

    float sA[4], ssA[4], sB[4], ssB[4];
#pragma unroll
    for (int q = 0; q < 4; ++q) { sA[q] = ssA[q] = sB[q] = ssB[q] = 0.f; }

    float4 va[4], vb[4];
    int4 ci;

    auto LOAD = [&](int kt) {
        const int base = win0 + kt * kKT + cg * 4;
#pragma unroll
        for (int q = 0; q < 4; ++q) {
            const int row = 64 * q + rbase;
            va[q] = *(const float4*)(zb  + (size_t)row * kHW + base);
            vb[q] = *(const float4*)(zpb + (size_t)row * kHW + base);
        }
        ci = *(const int4*)(cb + base);
    };

    auto CONVERT = [&](int buf) {
        char* As = smem + buf * 32768;
        char* Bs = As + 16384;
        const float cf[4] = {(float)ci.x, (float)ci.y, (float)ci.z, (float)ci.w};
#pragma unroll
        for (int q = 0; q < 4; ++q) {
            const int row = 64 * q + rbase;
            const float a[4]  = {va[q].x, va[q].y, va[q].z, va[q].w};
            const float bb[4] = {vb[q].x, vb[q].y, vb[q].z, vb[q].w};
            ushort4 pa, pb;
            unsigned short* pav = (unsigned short*)&pa;
            unsigned short* pbv = (unsigned short*)&pb;
#pragma unroll
            for (int j = 0; j < 4; ++j) {
                const float wa = cf[j] * a[j];
                const float wb = cf[j] * bb[j];
                sA[q] += wa; ssA[q] += wa * a[j];
                sB[q] += wb; ssB[q] += wb * bb[j];
                pav[j] = f2bf(a[j]);    // A raw
                pbv[j] = f2bf(wb);      // B weighted
            }
            // 64B rows; slot ^= (row>>1)&3 -> 8 consecutive rows cover all banks
            const int off = row * 64 + (((cg >> 1) ^ ((row >> 1) & 3)) << 4)
                          + ((cg & 1) << 3);
            *(ushort4*)(As + off) = pa;
            *(ushort4*)(Bs + off) = pb;
        }
    };

    LOAD(0);
    CONVERT(0);
    LOAD(1);
    __syncthreads();

    for (int kt = 0; kt < kNIter; ++kt) {
        const char* As = smem + (kt & 1) * 32768;
        const char* Bs = As + 16384;
#pragma unroll
        for (int ks = 0; ks < 2; ++ks) {
            s16x8 af[4], bfr[2];
#pragma unroll
            for (int rt = 0; rt < 4; ++rt) {
                const int row = 128 * wr + 32 * rt + l31;
                const int o = (2 * ks + half) ^ ((row >> 1) & 3);
                af[rt] = *(const s16x8*)(As + row * 64 + o * 16);
            }
#pragma unroll
            for (int ct = 0; ct < 2; ++ct) {
                const int row = 64 * wc + 32 * ct + l31;
                const int o = (2 * ks + half) ^ ((row >> 1) & 3);
                bfr[ct] = *(const s16x8*)(Bs + row * 64 + o * 16);
            }
#pragma unroll
            for (int rt = 0; rt < 4; ++rt)
#pragma unroll
                for (int ct = 0; ct < 2; ++ct)
                    acc[rt][ct] = __builtin_amdgcn_mfma_f32_32x32x16_bf16(
                        af[rt], bfr[ct], acc[rt][ct], 0, 0, 0);
        }
        __syncthreads();                 // all reads of this buf done
        if (kt < kNIter - 1) {
            CONVERT((kt + 1) & 1);       // consumes regs (vmcnt waits here)
            if (kt < kNIter - 2) LOAD(kt + 2);   // refill regs, issue early
        }
        __syncthreads();                 // writes to next buf complete
    }

    // 256x256 partial Gram
    float* out = partial + (size_t)bx * (kD * kD);
#pragma unroll
    for (int rt = 0; rt < 4; ++rt)
#pragma unroll
        for (int ct = 0; ct < 2; ++ct)
#pragma unroll
            for (int r = 0; r < 16; ++r) {
                const int row = 128 * wr + 32 * rt + (r & 3) + 8 * (r >> 2) + 4 * half;
                const int col = 64 * wc + 32 * ct + l31;
                out[row * kD + col] = acc[rt][ct][r];
            }

    // stats partial reduce via (dead) LDS: sd[256 rows][8 cg][4 kinds] = 32KB
    float* sd = (float*)smem;
#pragma unroll
    for (int q = 0; q < 4; ++q) {
        const int row = 64 * q + rbase;
        float* p = sd + (row * 8 + cg) * 4;
        p[0] = sA[q]; p[1] = ssA[q]; p[2] = sB[q]; p[3] = ssB[q];
    }
    __syncthreads();
    {
        const int row = t >> 1;
        const int pair = t & 1;
        float a0 = 0.f, a1 = 0.f;
#pragma unroll
        for (int g = 0; g < 8; ++g) {
            a0 += sd[(row * 8 + g) * 4 + 2 * pair];
            a1 += sd[(row * 8 + g) * 4 + 2 * pair + 1];
        }
        float* p = statsPart + ((size_t)bx * kD + row) * 4;
        p[2 * pair] = a0;
        p[2 * pair + 1] = a1;
    }
}

// ---------------------------------------------------------------------------
// Kernel 3: reduce partial Grams -> G (256x256 f32)
// ---------------------------------------------------------------------------
__global__ __launch_bounds__(256) void reduce_gram_kernel(
    const float* __restrict__ partial, float* __restrict__ G)
{
    const int d = blockIdx.x;
    const int e = threadIdx.x;
    float s = 0.f;
#pragma unroll 8
    for (int c = 0; c < kNBlk; ++c)
        s += partial[(size_t)c * (kD * kD) + d * kD + e];
    G[d * kD + e] = s;
}

// ---------------------------------------------------------------------------
// Kernel 4: final loss (single block).
// ---------------------------------------------------------------------------
__global__ __launch_bounds__(256) void loss_kernel(
    const float* __restrict__ G, const float* __restrict__ statsPart,
    float* __restrict__ out)
{
    __shared__ float muA[kD], isA[kD], muB[kD], isB[kD];
    const int t = threadIdx.x;
    float sA = 0.f, ssA = 0.f, sB = 0.f, ssB = 0.f;
    for (int blk = 0; blk < kNBlk; ++blk) {
        const float4 v = *(const float4*)(statsPart + ((size_t)blk * kD + t) * 4);
        sA += v.x; ssA += v.y; sB += v.z; ssB += v.w;
    }
    const float n = (float)kN;
    const float mA = sA / n, mB = sB / n;
    const float vA = (ssA - n * mA * mA) / (n - 1.f);
    const float vB = (ssB - n * mB * mB) / (n - 1.f);
    const float sdA = fmaxf(sqrtf(fmaxf(vA, 0.f)), 1e-6f);
    const float sdB = fmaxf(sqrtf(fmaxf(vB, 0.f)), 1e-6f);
    muA[t] = mA; isA[t] = 1.f / sdA;
    muB[t] = mB; isB[t] = 1.f / sdB;
    __syncthreads();

    float acc = 0.f;
    for (int d = 0; d < kD; ++d) {
        const int e = t;
        const float c = (G[d * kD + e] / n - muA[d] * muB[e]) * isA[d] * isB[e];
        if (d == e) { const float u = 1.f - c; acc += u * u; }
        else        { acc += kLam * c * c; }
    }
#pragma unroll
    for (int o = 32; o; o >>= 1) acc += __shfl_down(acc, o);
    __shared__ float r[4];
    if ((t & 63) == 0) r[t >> 6] = acc;
    __syncthreads();
    if (t == 0) out[0] = r[0] + r[1] + r[2] + r[3];
}

// ---------------------------------------------------------------------------
extern "C" void kernel_launch(void* const* d_in, const int* in_sizes, int n_in,
                              void* d_out, int out_size, void* d_ws, size_t ws_size,
                              hipStream_t stream) {
    const float* z  = (const float*)d_in[0];
    const float* zp = (const float*)d_in[1];
    const int* flat_idx = (const int*)d_in[2];
    float* out = (float*)d_out;

    char* ws = (char*)d_ws;
    // ws layout:
    //   [0, 1MB)     counts  int [16][16384]
    //   [1MB, 2MB)   statsPart f32 [256][256][4]
    //   [2MB, +256K) G f32 [256][256]
    //   [16MB, 80MB) partial f32 [256][256][256]
    int* cnt = (int*)ws;
    float* statsPart = (float*)(ws + (size_t)1 * 1024 * 1024);
    float* G = (float*)(ws + (size_t)2 * 1024 * 1024);
    float* partial = (float*)(ws + (size_t)16 * 1024 * 1024);

    count_kernel<<<kB, 256, 0, stream>>>(flat_idx, cnt);
    fused_gram_kernel<<<kNBlk, 512, 0, stream>>>(z, zp, cnt, partial, statsPart);
    reduce_gram_kernel<<<kD, 256, 0, stream>>>(partial, G);
    loss_kernel<<<1, 256, 0, stream>>>(G, statsPart, out);
}